// Round 1
// baseline (311.816 us; speedup 1.0000x reference)
//
#include <hip/hip_runtime.h>
#include <math.h>

#define N_TOK 131072
#define N_E   1024
#define E_DIM 64
#define BETA  0.4

// d_out layout (float32, concatenated in return order):
#define ZQ_OFF   0
#define LOSS_OFF 8388608
#define IDX_OFF  8388609
#define PERP_OFF 8519681

// d_ws layout (round-2 pass proved ws_size >= 532492; we use 336 KB):
#define WS_C2    0        // 1024 f32: RN32(exact ||c_e||^2)
#define WS_CNT   4096     // 1024 i32 counts
#define WS_SSQ   8192     // double sum_sq
#define WS_WLC   8200     // int worklist count (+4 pad)
#define WS_FH    8208     // 131072 B: fp16(codebook * 1024), MFMA B-frag layout
#define WS_WL    139280   // 16384 ints: worklist (flagged token ids)
#define WS_KEYS  204816   // 16384 u64: packed (d_bits<<32)|e per worklist slot
#define WLCAP    16384

typedef _Float16 f16x8 __attribute__((ext_vector_type(8)));
typedef float f32x4  __attribute__((ext_vector_type(4)));
typedef unsigned long long u64;

__device__ __forceinline__ void gl2lds16(const void* g, void* l) {
    __builtin_amdgcn_global_load_lds(
        (const __attribute__((address_space(1))) unsigned int*)g,
        (__attribute__((address_space(3))) unsigned int*)l, 16, 0, 0);
}

// Codebook -> fp16 MFMA B-fragment layout, scaled by 1024 (exact pow2) to keep
// all magnitudes >> fp16 denormal range. Also: exact-f32 c2 (first 1024 tids),
// counts/wlc/sum_sq zero-init, keys init (replaces the old c2_kernel + memsets).
__global__ void frag_kernel(const float* __restrict__ cb,
                            unsigned short* __restrict__ fh,
                            u64* __restrict__ keys,
                            float* __restrict__ c2,
                            int* __restrict__ counts, int* __restrict__ wlc,
                            double* __restrict__ sum_sq) {
    int tid = blockIdx.x * 256 + threadIdx.x;   // 65536 total
    if (tid < WLCAP) keys[tid] = ~0ull;
    if (tid < N_E) {
        const float* p = cb + (size_t)tid * E_DIM;
        double s = 0.0;
#pragma unroll
        for (int k = 0; k < E_DIM; ++k) {
            double c = (double)p[k];
            s = fma(c, c, s);
        }
        c2[tid] = (float)s;
        counts[tid] = 0;
        if (tid == 0) { *wlc = 0; *sum_sq = 0.0; }
    }
    int j  = tid & 7;
    int l  = (tid >> 3) & 63;
    int cc = tid >> 9;
    int code = (cc >> 1) * 16 + (l & 15);
    int k    = (cc & 1) * 32 + (l >> 4) * 8 + j;
    float f = cb[(size_t)code * E_DIM + k] * 1024.0f;  // exact pow2 scale
    union { _Float16 h; unsigned short s; } cv;
    cv.h = (_Float16)f;                                 // RN f32->f16
    fh[tid] = cv.s;
}

// Cold path (worklist overflow only). Exact numpy-f32 semantics, serial.
__device__ __attribute__((noinline)) int exact_best_serial(
    const float* __restrict__ z, const float* __restrict__ cb,
    const float* __restrict__ c2, int n) {
    const float* zr = z + (size_t)n * E_DIM;
    float r[8];
#pragma unroll
    for (int j = 0; j < 8; ++j) r[j] = __fmul_rn(zr[j], zr[j]);
#pragma unroll 1
    for (int i = 8; i < 64; i += 8)
#pragma unroll
        for (int j = 0; j < 8; ++j)
            r[j] = __fadd_rn(r[j], __fmul_rn(zr[i + j], zr[i + j]));
    float z2 = __fadd_rn(__fadd_rn(__fadd_rn(r[0], r[1]), __fadd_rn(r[2], r[3])),
                         __fadd_rn(__fadd_rn(r[4], r[5]), __fadd_rn(r[6], r[7])));
    u64 bestkey = ~0ull;
#pragma unroll 1
    for (int e = 0; e < N_E; ++e) {
        const float* cp = cb + (size_t)e * E_DIM;
        double m = 0.0;
#pragma unroll 1
        for (int i = 0; i < E_DIM; ++i)
            m = fma((double)zr[i], (double)cp[i], m);
        float d = __fsub_rn(__fadd_rn(z2, c2[e]), __fmul_rn(2.0f, (float)m));
        u64 key = ((u64)__float_as_uint(d) << 32) | (unsigned)e;
        if (key < bestkey) bestkey = key;
    }
    return (int)(bestkey & 0xffffffffu);
}

// Screen: 1024 blocks x 128 tokens, 4 blocks/CU. fp16 single-product screen
// (error ~2e-6 rms in original-u units, covered by widened margin + exact
// fixup). 8 stages x 128 codes; single barrier per stage. Track max of
// u'' = 1024*dot - 512*c2 + 64 (> 0), key = (bits&~63)|(63-c).
__global__ __launch_bounds__(256, 4) void vq_main(
    const float* __restrict__ z, const float* __restrict__ cb,
    const float* __restrict__ c2, const unsigned short* __restrict__ fh_,
    int* __restrict__ counts, double* __restrict__ sum_sq,
    int* __restrict__ wl_count, int* __restrict__ wl, float margin_u,
    float* __restrict__ out) {

    __shared__ unsigned char stagebuf[2][16384];  // double-buffered fp16 stage
    __shared__ float c2s[N_E];                    // 64 - 512*c2
    __shared__ int   best_s[128];
    __shared__ unsigned char flag_s[128];
    __shared__ double wred[4];

    const int tid  = threadIdx.x;
    const int lane = tid & 63;
    const int wid  = tid >> 6;
    const int col  = lane & 15;
    const int quad = lane >> 4;
    const int blk_tok0 = blockIdx.x * 128;
    const int wave_tok0 = blk_tok0 + wid * 32;

    const char* hsrc0 = (const char*)fh_;
    auto stage = [&](int s, int b) {
#pragma unroll
        for (int i = 0; i < 4; ++i)
            gl2lds16(hsrc0 + s * 16384 + i * 4096 + tid * 16,
                     &stagebuf[b][i * 4096 + wid * 1024]);
    };

    stage(0, 0);   // issue codebook staging first; overlaps z loads below

#pragma unroll
    for (int i = 0; i < 4; ++i)
        c2s[tid * 4 + i] = fmaf(-512.0f, c2[tid * 4 + i], 64.0f);

    // A fragments: 2 tiles x 2 k-chunks, fp16 (z unscaled; |z|<~6 fits fp16)
    f16x8 Ah[2][2];
#pragma unroll
    for (int m = 0; m < 2; ++m) {
        const float* zr = z + (size_t)(wave_tok0 + m * 16 + col) * E_DIM + quad * 8;
#pragma unroll
        for (int kc = 0; kc < 2; ++kc) {
            float4 u0 = *(const float4*)(zr + kc * 32);
            float4 u1 = *(const float4*)(zr + kc * 32 + 4);
            f16x8 a;
            a[0] = (_Float16)u0.x; a[1] = (_Float16)u0.y;
            a[2] = (_Float16)u0.z; a[3] = (_Float16)u0.w;
            a[4] = (_Float16)u1.x; a[5] = (_Float16)u1.y;
            a[6] = (_Float16)u1.z; a[7] = (_Float16)u1.w;
            Ah[m][kc] = a;
        }
    }

    // packed-key top-2 MAX tracker
    unsigned k1[2][4], k2[2][4];
#pragma unroll
    for (int m = 0; m < 2; ++m)
#pragma unroll
        for (int r = 0; r < 4; ++r) { k1[m][r] = 0u; k2[m][r] = 0u; }

    for (int s = 0; s < 8; ++s) {
        __syncthreads();              // drains vmcnt -> staged data for s ready
        if (s + 1 < 8) stage(s + 1, (s + 1) & 1);
        const unsigned char* hb = &stagebuf[s & 1][0];
#pragma unroll
        for (int cl = 0; cl < 8; ++cl) {
            const int c = s * 8 + cl;
            const int off0 = cl * 2048 + lane * 16;
            union { uint4 u; f16x8 v; } b0, b1;
            b0.u = *(const uint4*)(hb + off0);
            b1.u = *(const uint4*)(hb + off0 + 1024);
            const float ch = c2s[c * 16 + col];
            const f32x4 cinit = {ch, ch, ch, ch};
            const unsigned ctag = (unsigned)(63 - c);
#pragma unroll
            for (int m = 0; m < 2; ++m) {
                f32x4 acc = __builtin_amdgcn_mfma_f32_16x16x32_f16(
                    Ah[m][0], b0.v, cinit, 0, 0, 0);
                acc = __builtin_amdgcn_mfma_f32_16x16x32_f16(
                    Ah[m][1], b1.v, acc, 0, 0, 0);
#pragma unroll
                for (int r = 0; r < 4; ++r) {
                    unsigned key = (__float_as_uint(acc[r]) & 0xFFFFFFC0u) | ctag;
                    unsigned hi2 = min(k1[m][r], key);
                    k2[m][r] = max(k2[m][r], hi2);
                    k1[m][r] = max(k1[m][r], key);
                }
            }
        }
    }

    // merge + decide, per (m,r): maximize u'', tie -> lowest code index
#pragma unroll
    for (int m = 0; m < 2; ++m) {
#pragma unroll
        for (int r = 0; r < 4; ++r) {
            float v1 = __uint_as_float(k1[m][r] & 0xFFFFFFC0u);
            float v2 = __uint_as_float(k2[m][r] & 0xFFFFFFC0u);
            int   b1 = (63 - (int)(k1[m][r] & 63u)) * 16 + col;
#pragma unroll
            for (int d = 1; d < 16; d <<= 1) {
                float o1 = __shfl_xor(v1, d, 64);
                float o2 = __shfl_xor(v2, d, 64);
                int   ob = __shfl_xor(b1, d, 64);
                float n2 = fmaxf(fmaxf(v2, o2), fminf(v1, o1));
                bool take = (o1 > v1) || (o1 == v1 && ob < b1);
                v1 = fmaxf(v1, o1);
                b1 = take ? ob : b1;
                v2 = n2;
            }
            if (col == 0) {
                int tl = wid * 32 + m * 16 + quad * 4 + r;
                int n  = blk_tok0 + tl;
                int best = b1;
                bool fl = (v1 - v2) < margin_u;
                if (fl) {
                    int pos = atomicAdd(wl_count, 1);
                    if (pos < WLCAP) wl[pos] = n;
                    else { best = exact_best_serial(z, cb, c2, n); fl = false; }
                }
                best_s[tl] = best;
                flag_s[tl] = fl ? 1 : 0;
                if (!fl) atomicAdd(&counts[best], 1);
            }
        }
    }
    __syncthreads();

    // coalesced idx write (flagged slots overwritten later by fixup_apply)
    if (tid < 128) out[IDX_OFF + blk_tok0 + tid] = (float)best_s[tid];

    // epilogue: coalesced z_q / loss for unflagged tokens (exact f32 z re-read)
    const int sub = tid & 15, grp = tid >> 4;
    double dl = 0.0;
    const float4* zrow = (const float4*)z;
    const float4* crow = (const float4*)cb;
    float4* qrow = (float4*)(out + ZQ_OFF);
#pragma unroll
    for (int p = 0; p < 8; ++p) {
        int tl = p * 16 + grp;
        if (!flag_s[tl]) {
            int n = blk_tok0 + tl;
            float4 z4 = zrow[(size_t)n * 16 + sub];
            float4 c4 = crow[(size_t)best_s[tl] * 16 + sub];
            float dx = c4.x - z4.x, dy = c4.y - z4.y;
            float dz = c4.z - z4.z, dw = c4.w - z4.w;
            float4 q;
            q.x = z4.x + dx; q.y = z4.y + dy;
            q.z = z4.z + dz; q.w = z4.w + dw;
            qrow[(size_t)n * 16 + sub] = q;
            dl += (double)dx * dx + (double)dy * dy
                + (double)dz * dz + (double)dw * dw;
        }
    }
#pragma unroll
    for (int off = 32; off > 0; off >>= 1)
        dl += __shfl_down(dl, off, 64);
    if (lane == 0) wred[wid] = dl;
    __syncthreads();
    if (tid == 0)
        atomicAdd(sum_sq, wred[0] + wred[1] + wred[2] + wred[3]);
}

// Scan: one wave per (64-token group x 32-code slice); token-per-lane,
// wave-uniform cb rows. z2 (numpy pairwise) computed inline from exact z.
__global__ __launch_bounds__(64) void fixup_scan(
    const float* __restrict__ z, const float* __restrict__ cb,
    const float* __restrict__ c2, const int* __restrict__ wl,
    const int* __restrict__ wl_count, u64* __restrict__ keys) {

    int count = *wl_count; if (count > WLCAP) count = WLCAP;
    const int g = blockIdx.x >> 5;        // token group (64 per group)
    const int s = blockIdx.x & 31;        // code slice (32 codes)
    if (g * 64 >= count) return;
    const int lane = threadIdx.x;
    const int w = g * 64 + lane;
    const bool valid = w < count;
    const int n = wl[valid ? w : g * 64];

    double zd[E_DIM];
    const float4* zp = (const float4*)(z + (size_t)n * E_DIM);
#pragma unroll
    for (int k = 0; k < 16; ++k) {
        float4 v = zp[k];
        zd[4 * k]     = (double)v.x;
        zd[4 * k + 1] = (double)v.y;
        zd[4 * k + 2] = (double)v.z;
        zd[4 * k + 3] = (double)v.w;
    }
    // numpy-pairwise z2 in f32 (8 accumulators + tree); (float)zd is exact
    float r8[8];
#pragma unroll
    for (int j = 0; j < 8; ++j) {
        float f = (float)zd[j];
        r8[j] = __fmul_rn(f, f);
    }
#pragma unroll
    for (int i = 8; i < 64; i += 8)
#pragma unroll
        for (int j = 0; j < 8; ++j) {
            float f = (float)zd[i + j];
            r8[j] = __fadd_rn(r8[j], __fmul_rn(f, f));
        }
    const float z2 = __fadd_rn(
        __fadd_rn(__fadd_rn(r8[0], r8[1]), __fadd_rn(r8[2], r8[3])),
        __fadd_rn(__fadd_rn(r8[4], r8[5]), __fadd_rn(r8[6], r8[7])));

    u64 best = ~0ull;
    const int e0 = s * 32;
    for (int e = e0; e < e0 + 32; ++e) {
        const float* cp = cb + (size_t)e * E_DIM;   // wave-uniform row
        double m = 0.0;
#pragma unroll
        for (int i = 0; i < E_DIM; ++i)
            m = fma(zd[i], (double)cp[i], m);
        float d = __fsub_rn(__fadd_rn(z2, c2[e]), __fmul_rn(2.0f, (float)m));
        u64 key = ((u64)__float_as_uint(d) << 32) | (unsigned)e;
        if (key < best) best = key;
    }
    if (valid) atomicMin(&keys[w], best);
}

// Apply: one wave per worklist token; finish zq/idx/counts/sum_sq.
__global__ __launch_bounds__(256) void fixup_apply(
    const float* __restrict__ z, const float* __restrict__ cb,
    const int* __restrict__ wl, const int* __restrict__ wl_count,
    const u64* __restrict__ keys, int* __restrict__ counts,
    double* __restrict__ sum_sq, float* __restrict__ out) {

    int count = *wl_count; if (count > WLCAP) count = WLCAP;
    const int lane = threadIdx.x & 63;
    const int gw = blockIdx.x * 4 + (threadIdx.x >> 6);
    for (int w = gw; w < count; w += 1024) {
        const int n = wl[w];
        const int best = (int)(keys[w] & 0xffffffffull);
        float cv = cb[(size_t)best * E_DIM + lane];
        float zi = z[(size_t)n * E_DIM + lane];
        float diff = cv - zi;
        out[ZQ_OFF + (size_t)n * E_DIM + lane] = zi + diff;
        double d2 = (double)diff * (double)diff;
#pragma unroll
        for (int off = 32; off > 0; off >>= 1)
            d2 += __shfl_down(d2, off, 64);
        if (lane == 0) {
            atomicAdd(sum_sq, d2);
            atomicAdd(&counts[best], 1);
            out[IDX_OFF + n] = (float)best;
        }
    }
}

__global__ __launch_bounds__(1024) void finalize_kernel(
    const int* __restrict__ counts, const double* __restrict__ sum_sq,
    float* __restrict__ out) {
    __shared__ double red[1024];
    int e = threadIdx.x;
    double em = (double)counts[e] / (double)N_TOK;
    red[e] = -em * log(em + 1e-10);
    __syncthreads();
    for (int s = 512; s > 0; s >>= 1) {
        if (e < s) red[e] += red[e + s];
        __syncthreads();
    }
    if (e == 0) {
        double usage = red[0];
        double mse = sum_sq[0] / (double)((size_t)N_TOK * E_DIM);
        out[LOSS_OFF] = (float)((1.0 + BETA) * mse + 0.01 * usage);
        out[PERP_OFF] = (float)exp(usage);
    }
}

extern "C" void kernel_launch(void* const* d_in, const int* in_sizes, int n_in,
                              void* d_out, int out_size, void* d_ws, size_t ws_size,
                              hipStream_t stream) {
    const float* z  = (const float*)d_in[0];
    const float* cb = (const float*)d_in[1];
    float* out = (float*)d_out;

    float*          c2     = (float*)((char*)d_ws + WS_C2);
    int*            counts = (int*)((char*)d_ws + WS_CNT);
    double*         sum_sq = (double*)((char*)d_ws + WS_SSQ);
    int*            wlc    = (int*)((char*)d_ws + WS_WLC);
    unsigned short* fh     = (unsigned short*)((char*)d_ws + WS_FH);
    int*            wl     = (int*)((char*)d_ws + WS_WL);
    u64*            keys   = (u64*)((char*)d_ws + WS_KEYS);

    // u''-space margin (scaled x1024): 0.07 = 6.8e-5 original-u = 2.25e-5
    // (validated exact-screen base) + 4.6e-5 fp16 screen-error budget
    // (Hoeffding tail < 1e-6 over all tokens). Expected flags ~5k << 16384.
    float margin_u = (ws_size >= (size_t)(WS_KEYS + 8 * WLCAP)) ? 0.07f : 0.0f;

    frag_kernel<<<256, 256, 0, stream>>>(cb, fh, keys, c2, counts, wlc, sum_sq);
    vq_main<<<1024, 256, 0, stream>>>(z, cb, c2, fh, counts, sum_sq,
                                      wlc, wl, margin_u, out);
    fixup_scan<<<8192, 64, 0, stream>>>(z, cb, c2, wl, wlc, keys);
    fixup_apply<<<256, 256, 0, stream>>>(z, cb, wl, wlc, keys, counts,
                                         sum_sq, out);
    finalize_kernel<<<1, 1024, 0, stream>>>(counts, sum_sq, out);
}